// Round 1
// baseline (2996.873 us; speedup 1.0000x reference)
//
#include <hip/hip_runtime.h>
#include <math.h>

#define BB   2
#define TT   2048
#define DD   2048
#define HH   16
#define KVHN 4
#define HDIM 128

// ---------------- GEMM: C[M,N] = A[M,K] @ B[K,N], fp32 --------------------
// 128x128 tile, K-tile 16, 256 threads, 8x8 per thread, float4 LDS reads.
__global__ __launch_bounds__(256) void gemm_f32(const float* __restrict__ A,
                                                const float* __restrict__ Bm,
                                                float* __restrict__ C,
                                                int N, int K) {
  __shared__ float As[16][128];   // As[k][m] (transposed store)
  __shared__ float Bs[16][128];   // Bs[k][n]
  const int t  = threadIdx.x;
  const int m0 = blockIdx.y * 128;
  const int n0 = blockIdx.x * 128;
  const int r0 = (t >> 4) * 8;
  const int c0 = (t & 15) * 8;
  float acc[8][8];
  #pragma unroll
  for (int i = 0; i < 8; ++i)
    #pragma unroll
    for (int j = 0; j < 8; ++j) acc[i][j] = 0.f;

  for (int k0 = 0; k0 < K; k0 += 16) {
    // A tile: 128 rows x 16 k, transposed into As[k][m]
    #pragma unroll
    for (int i = 0; i < 2; ++i) {
      int idx = t + i * 256;           // float4 index 0..511
      int row = idx >> 2;              // 0..127
      int kc  = (idx & 3) * 4;         // 0,4,8,12
      float4 av = *(const float4*)(A + (size_t)(m0 + row) * K + k0 + kc);
      As[kc + 0][row] = av.x;
      As[kc + 1][row] = av.y;
      As[kc + 2][row] = av.z;
      As[kc + 3][row] = av.w;
    }
    // B tile: 16 k x 128 n, direct
    #pragma unroll
    for (int i = 0; i < 2; ++i) {
      int idx = t + i * 256;
      int row = idx >> 5;              // 0..15
      int nc  = (idx & 31) * 4;
      *(float4*)&Bs[row][nc] = *(const float4*)(Bm + (size_t)(k0 + row) * N + n0 + nc);
    }
    __syncthreads();
    #pragma unroll
    for (int kk = 0; kk < 16; ++kk) {
      float4 a0 = *(const float4*)&As[kk][r0];
      float4 a1 = *(const float4*)&As[kk][r0 + 4];
      float4 b0 = *(const float4*)&Bs[kk][c0];
      float4 b1 = *(const float4*)&Bs[kk][c0 + 4];
      float av[8] = {a0.x, a0.y, a0.z, a0.w, a1.x, a1.y, a1.z, a1.w};
      float bv[8] = {b0.x, b0.y, b0.z, b0.w, b1.x, b1.y, b1.z, b1.w};
      #pragma unroll
      for (int i = 0; i < 8; ++i)
        #pragma unroll
        for (int j = 0; j < 8; ++j) acc[i][j] = fmaf(av[i], bv[j], acc[i][j]);
    }
    __syncthreads();
  }
  #pragma unroll
  for (int i = 0; i < 8; ++i) {
    float4 o0 = make_float4(acc[i][0], acc[i][1], acc[i][2], acc[i][3]);
    float4 o1 = make_float4(acc[i][4], acc[i][5], acc[i][6], acc[i][7]);
    float* cp = C + (size_t)(m0 + r0 + i) * N + n0 + c0;
    *(float4*)cp       = o0;
    *(float4*)(cp + 4) = o1;
  }
}

// ---------------- RoPE (in-place), optionally folds softmax scale ----------
// One block owns one (b,t) row -> read all, sync, write all: race-free.
// out[f] = in[2f]*cos - in[2f+1]*sin ; out[f+64] = in[2f]*sin + in[2f+1]*cos
__global__ __launch_bounds__(256) void rope_f32(float* p, int nHeads, float scale) {
  const int row = blockIdx.x;                  // b*T + t
  const int pos = row & (TT - 1);
  float* base = p + (size_t)row * nHeads * HDIM;
  const int per = (nHeads * 64) / 256;         // q: 4, k: 1
  float e0[4], e1[4];
  for (int i = 0; i < per; ++i) {
    int item = threadIdx.x + i * 256;
    int h = item >> 6, f = item & 63;
    e0[i] = base[h * HDIM + 2 * f];
    e1[i] = base[h * HDIM + 2 * f + 1];
  }
  __syncthreads();
  for (int i = 0; i < per; ++i) {
    int item = threadIdx.x + i * 256;
    int h = item >> 6, f = item & 63;
    float inv = expf((float)f * -0.14391156831212787f);  // 10000^(-f/64)
    float ang = (float)pos * inv;
    float sn = sinf(ang), cs = cosf(ang);
    base[h * HDIM + f]      = (e0[i] * cs - e1[i] * sn) * scale;
    base[h * HDIM + 64 + f] = (e0[i] * sn + e1[i] * cs) * scale;
  }
}

// ---------------- Flash attention, causal, GQA (g=4) ----------------------
// BQ=BK=32, 256 threads. q pre-scaled by 1/sqrt(HD). o may alias q:
// each (b,h,qt) output region is read only by its own block (at start).
__global__ __launch_bounds__(256) void attn_f32(const float* q, const float* kk,
                                                const float* vv, float* o) {
  __shared__ float Qs[32][132];
  __shared__ float Ks[32][132];
  __shared__ float Vs[32][132];
  __shared__ float Ss[32][33];
  __shared__ float alpha_s[32];
  __shared__ float l_s[32];
  const int t   = threadIdx.x;
  const int qt  = (int)gridDim.x - 1 - (int)blockIdx.x;  // heavy blocks first
  const int h   = blockIdx.y;
  const int b   = blockIdx.z;
  const int q0  = qt * 32;
  const int kvh = h >> 2;

  // load Q tile (scale already folded in by rope)
  #pragma unroll
  for (int i = 0; i < 4; ++i) {
    int idx = t + i * 256;
    int r = idx >> 5, dc = (idx & 31) * 4;
    *(float4*)&Qs[r][dc] =
        *(const float4*)(q + (size_t)(b * TT + q0 + r) * DD + h * HDIM + dc);
  }

  float m_r = -3.0e38f, l_r = 0.f;        // row state, owned by threads 0..31
  float acc[2][8];
  #pragma unroll
  for (int i = 0; i < 2; ++i)
    #pragma unroll
    for (int j = 0; j < 8; ++j) acc[i][j] = 0.f;

  const int rs0 = (t >> 4) * 2;           // S rows (also O rows)
  const int cs0 = (t & 15) * 2;           // S cols
  const int co0 = (t & 15) * 8;           // O cols

  for (int kt = 0; kt <= qt; ++kt) {
    const int k0 = kt * 32;
    __syncthreads();                      // protect Ks/Vs/Ss from prev readers
    #pragma unroll
    for (int i = 0; i < 4; ++i) {
      int idx = t + i * 256;
      int r = idx >> 5, dc = (idx & 31) * 4;
      size_t g = (size_t)(b * TT + k0 + r) * (KVHN * HDIM) + kvh * HDIM + dc;
      *(float4*)&Ks[r][dc] = *(const float4*)(kk + g);
      *(float4*)&Vs[r][dc] = *(const float4*)(vv + g);
    }
    __syncthreads();

    // S = Q K^T, 2x2 per thread
    float s00 = 0.f, s01 = 0.f, s10 = 0.f, s11 = 0.f;
    for (int d = 0; d < HDIM; d += 4) {
      float4 qv0 = *(const float4*)&Qs[rs0][d];
      float4 qv1 = *(const float4*)&Qs[rs0 + 1][d];
      float4 kv0 = *(const float4*)&Ks[cs0][d];
      float4 kv1 = *(const float4*)&Ks[cs0 + 1][d];
      s00 = fmaf(qv0.x, kv0.x, s00); s00 = fmaf(qv0.y, kv0.y, s00);
      s00 = fmaf(qv0.z, kv0.z, s00); s00 = fmaf(qv0.w, kv0.w, s00);
      s01 = fmaf(qv0.x, kv1.x, s01); s01 = fmaf(qv0.y, kv1.y, s01);
      s01 = fmaf(qv0.z, kv1.z, s01); s01 = fmaf(qv0.w, kv1.w, s01);
      s10 = fmaf(qv1.x, kv0.x, s10); s10 = fmaf(qv1.y, kv0.y, s10);
      s10 = fmaf(qv1.z, kv0.z, s10); s10 = fmaf(qv1.w, kv0.w, s10);
      s11 = fmaf(qv1.x, kv1.x, s11); s11 = fmaf(qv1.y, kv1.y, s11);
      s11 = fmaf(qv1.z, kv1.z, s11); s11 = fmaf(qv1.w, kv1.w, s11);
    }
    {
      int qr = q0 + rs0, kc = k0 + cs0;
      Ss[rs0][cs0]         = (qr     >= kc    ) ? s00 : -3.0e30f;
      Ss[rs0][cs0 + 1]     = (qr     >= kc + 1) ? s01 : -3.0e30f;
      Ss[rs0 + 1][cs0]     = (qr + 1 >= kc    ) ? s10 : -3.0e30f;
      Ss[rs0 + 1][cs0 + 1] = (qr + 1 >= kc + 1) ? s11 : -3.0e30f;
    }
    __syncthreads();

    // online softmax (threads 0..31 each own one row)
    if (t < 32) {
      float mx = -3.0e38f;
      #pragma unroll
      for (int c = 0; c < 32; ++c) mx = fmaxf(mx, Ss[t][c]);
      float m_new = fmaxf(m_r, mx);
      float al = expf(m_r - m_new);   // first iter: exp(-inf-ish) = 0
      float sum = 0.f;
      #pragma unroll
      for (int c = 0; c < 32; ++c) {
        float pp = expf(Ss[t][c] - m_new);
        Ss[t][c] = pp;
        sum += pp;
      }
      l_r = l_r * al + sum;
      m_r = m_new;
      alpha_s[t] = al;
    }
    __syncthreads();

    // O = O*alpha + P V, 2 rows x 8 cols per thread
    {
      float al0 = alpha_s[rs0], al1 = alpha_s[rs0 + 1];
      #pragma unroll
      for (int j = 0; j < 8; ++j) { acc[0][j] *= al0; acc[1][j] *= al1; }
    }
    for (int c = 0; c < 32; ++c) {
      float4 v0 = *(const float4*)&Vs[c][co0];
      float4 v1 = *(const float4*)&Vs[c][co0 + 4];
      float p0 = Ss[rs0][c], p1 = Ss[rs0 + 1][c];
      acc[0][0] = fmaf(p0, v0.x, acc[0][0]);
      acc[0][1] = fmaf(p0, v0.y, acc[0][1]);
      acc[0][2] = fmaf(p0, v0.z, acc[0][2]);
      acc[0][3] = fmaf(p0, v0.w, acc[0][3]);
      acc[0][4] = fmaf(p0, v1.x, acc[0][4]);
      acc[0][5] = fmaf(p0, v1.y, acc[0][5]);
      acc[0][6] = fmaf(p0, v1.z, acc[0][6]);
      acc[0][7] = fmaf(p0, v1.w, acc[0][7]);
      acc[1][0] = fmaf(p1, v0.x, acc[1][0]);
      acc[1][1] = fmaf(p1, v0.y, acc[1][1]);
      acc[1][2] = fmaf(p1, v0.z, acc[1][2]);
      acc[1][3] = fmaf(p1, v0.w, acc[1][3]);
      acc[1][4] = fmaf(p1, v1.x, acc[1][4]);
      acc[1][5] = fmaf(p1, v1.y, acc[1][5]);
      acc[1][6] = fmaf(p1, v1.z, acc[1][6]);
      acc[1][7] = fmaf(p1, v1.w, acc[1][7]);
    }
  }
  if (t < 32) l_s[t] = l_r;
  __syncthreads();
  {
    float inv0 = 1.f / l_s[rs0];
    float inv1 = 1.f / l_s[rs0 + 1];
    float* op0 = o + (size_t)(b * TT + q0 + rs0) * DD + h * HDIM + co0;
    float* op1 = op0 + DD;
    float4 w0 = make_float4(acc[0][0]*inv0, acc[0][1]*inv0, acc[0][2]*inv0, acc[0][3]*inv0);
    float4 w1 = make_float4(acc[0][4]*inv0, acc[0][5]*inv0, acc[0][6]*inv0, acc[0][7]*inv0);
    float4 w2 = make_float4(acc[1][0]*inv1, acc[1][1]*inv1, acc[1][2]*inv1, acc[1][3]*inv1);
    float4 w3 = make_float4(acc[1][4]*inv1, acc[1][5]*inv1, acc[1][6]*inv1, acc[1][7]*inv1);
    *(float4*)op0       = w0;
    *(float4*)(op0 + 4) = w1;
    *(float4*)op1       = w2;
    *(float4*)(op1 + 4) = w3;
  }
}

extern "C" void kernel_launch(void* const* d_in, const int* in_sizes, int n_in,
                              void* d_out, int out_size, void* d_ws, size_t ws_size,
                              hipStream_t stream) {
  const float* x  = (const float*)d_in[0];
  const float* Wq = (const float*)d_in[1];
  const float* Wk = (const float*)d_in[2];
  const float* Wv = (const float*)d_in[3];
  const float* Wo = (const float*)d_in[4];
  float* out = (float*)d_out;

  // workspace layout: q (B*T*D) | k (B*T*512) | v (B*T*512)  = 48 MB
  float* q = (float*)d_ws;
  float* k = q + (size_t)BB * TT * DD;
  float* v = k + (size_t)BB * TT * KVHN * HDIM;

  dim3 blk(256);
  const int M = BB * TT;                      // 4096
  // projections
  gemm_f32<<<dim3(DD / 128, M / 128), blk, 0, stream>>>(x, Wq, q, DD, DD);
  gemm_f32<<<dim3((KVHN * HDIM) / 128, M / 128), blk, 0, stream>>>(x, Wk, k, KVHN * HDIM, DD);
  gemm_f32<<<dim3((KVHN * HDIM) / 128, M / 128), blk, 0, stream>>>(x, Wv, v, KVHN * HDIM, DD);
  // rope (scale 1/sqrt(128) folded into q)
  rope_f32<<<BB * TT, 256, 0, stream>>>(q, HH, 0.08838834764831845f);
  rope_f32<<<BB * TT, 256, 0, stream>>>(k, KVHN, 1.0f);
  // attention, output written in-place over q
  attn_f32<<<dim3(TT / 32, HH, BB), blk, 0, stream>>>(q, k, v, q);
  // output projection
  gemm_f32<<<dim3(DD / 128, M / 128), blk, 0, stream>>>(q, Wo, out, DD, DD);
}

// Round 2
// 497.067 us; speedup vs baseline: 6.0291x; 6.0291x over previous
//
#include <hip/hip_runtime.h>
#include <math.h>

#define BB   2
#define TT   2048
#define DD   2048
#define HH   16
#define KVHN 4
#define HDIM 128

typedef unsigned short u16;
typedef unsigned int   u32;
typedef __bf16 bf16x8 __attribute__((ext_vector_type(8)));
typedef float  f32x4  __attribute__((ext_vector_type(4)));

__device__ __forceinline__ u16 f2bf(float f) {
  u32 u = __float_as_uint(f);
  u32 r = (u + 0x7FFFu + ((u >> 16) & 1u)) >> 16;
  return (u16)r;
}
__device__ __forceinline__ float bf2f(u32 h) {
  return __uint_as_float(h << 16);
}

// ---------------- cast fp32 -> bf16 (elementwise, 4/thread) ----------------
__global__ __launch_bounds__(256) void castf2b(const float* __restrict__ in,
                                               u16* __restrict__ out) {
  size_t i4 = (size_t)blockIdx.x * 256 + threadIdx.x;
  float4 v = *(const float4*)(in + i4 * 4);
  ushort4 o;
  o.x = f2bf(v.x); o.y = f2bf(v.y); o.z = f2bf(v.z); o.w = f2bf(v.w);
  *(ushort4*)(out + i4 * 4) = o;
}

// ---------------- transpose + cast: W[K][N] fp32 -> WT[N][K] bf16 ----------
__global__ __launch_bounds__(256) void tcast(const float* __restrict__ W,
                                             u16* __restrict__ WT,
                                             int K, int N) {
  __shared__ float tile[32][33];
  const int n0 = blockIdx.x * 32, k0 = blockIdx.y * 32;
  const int r = threadIdx.x >> 3;
  const int c4 = (threadIdx.x & 7) * 4;
  float4 v = *(const float4*)(W + (size_t)(k0 + r) * N + n0 + c4);
  tile[r][c4 + 0] = v.x; tile[r][c4 + 1] = v.y;
  tile[r][c4 + 2] = v.z; tile[r][c4 + 3] = v.w;
  __syncthreads();
  ushort4 o;
  o.x = f2bf(tile[c4 + 0][r]); o.y = f2bf(tile[c4 + 1][r]);
  o.z = f2bf(tile[c4 + 2][r]); o.w = f2bf(tile[c4 + 3][r]);
  *(ushort4*)(WT + (size_t)(n0 + r) * K + k0 + c4) = o;
}

// ---------------- MFMA GEMM: C[M,N] = A[M,K] @ BT[N,K]^T ------------------
// 128x128 tile, BK=32, 256 thr = 4 waves (2x2), each wave 4x4 16x16 frags.
// LDS row stride 40 (32 data + 8 pad) -> uniform bank coverage for b128.
template <int OUT_BF16>
__global__ __launch_bounds__(256) void gemm_bf16(const u16* __restrict__ A,
                                                 const u16* __restrict__ BT,
                                                 void* __restrict__ Cv,
                                                 int N, int K) {
  __shared__ u16 As[128 * 40];
  __shared__ u16 Bs[128 * 40];
  const int t = threadIdx.x;
  const int l = t & 63, w = t >> 6;
  const int lm = l & 15, quad = l >> 4;
  const int wm = w & 1, wn = w >> 1;
  const int m0 = blockIdx.y * 128, n0 = blockIdx.x * 128;

  f32x4 acc[4][4];
  #pragma unroll
  for (int i = 0; i < 4; ++i)
    #pragma unroll
    for (int j = 0; j < 4; ++j) acc[i][j] = (f32x4){0.f, 0.f, 0.f, 0.f};

  for (int k0 = 0; k0 < K; k0 += 32) {
    __syncthreads();
    #pragma unroll
    for (int i = 0; i < 2; ++i) {
      int c = t + i * 256;                 // 0..511 16B chunks
      int row = c >> 2, kc = (c & 3) * 8;
      *(uint4*)&As[row * 40 + kc] = *(const uint4*)(A + (size_t)(m0 + row) * K + k0 + kc);
      *(uint4*)&Bs[row * 40 + kc] = *(const uint4*)(BT + (size_t)(n0 + row) * K + k0 + kc);
    }
    __syncthreads();
    bf16x8 a[4], b[4];
    #pragma unroll
    for (int i = 0; i < 4; ++i)
      a[i] = *(const bf16x8*)&As[(wm * 64 + i * 16 + lm) * 40 + quad * 8];
    #pragma unroll
    for (int j = 0; j < 4; ++j)
      b[j] = *(const bf16x8*)&Bs[(wn * 64 + j * 16 + lm) * 40 + quad * 8];
    #pragma unroll
    for (int i = 0; i < 4; ++i)
      #pragma unroll
      for (int j = 0; j < 4; ++j)
        acc[i][j] = __builtin_amdgcn_mfma_f32_16x16x32_bf16(a[i], b[j], acc[i][j], 0, 0, 0);
  }

  // epilogue: D[row=quad*4+r][col=lm] per 16x16 frag
  #pragma unroll
  for (int i = 0; i < 4; ++i) {
    #pragma unroll
    for (int r = 0; r < 4; ++r) {
      size_t gr = (size_t)(m0 + wm * 64 + i * 16 + quad * 4 + r);
      #pragma unroll
      for (int j = 0; j < 4; ++j) {
        int gc = n0 + wn * 64 + j * 16 + lm;
        if (OUT_BF16) ((u16*)Cv)[gr * N + gc] = f2bf(acc[i][j][r]);
        else          ((float*)Cv)[gr * N + gc] = acc[i][j][r];
      }
    }
  }
}

// ---------------- RoPE in-place on bf16 rows ------------------------------
// One block per (b,t) row: read-all, sync, write-all (race-free).
__global__ __launch_bounds__(256) void rope_bf16(u16* p, int rowStride,
                                                 int nHeads, float scale) {
  const int row = blockIdx.x;
  const int pos = row & (TT - 1);
  u16* base = p + (size_t)row * rowStride;
  const int per = (nHeads * 64) >> 8;          // q:4, k:1
  float e0[4], e1[4];
  for (int i = 0; i < per; ++i) {
    int item = threadIdx.x + i * 256;
    int h = item >> 6, f = item & 63;
    u32 u = *(const u32*)(base + h * 128 + 2 * f);
    e0[i] = bf2f(u & 0xffffu);
    e1[i] = bf2f(u >> 16);
  }
  __syncthreads();
  for (int i = 0; i < per; ++i) {
    int item = threadIdx.x + i * 256;
    int h = item >> 6, f = item & 63;
    float inv = exp2f((float)f * -0.20762050593046898f);  // 10000^(-f/64)
    float ang = (float)pos * inv;
    float sn = sinf(ang), cs = cosf(ang);
    base[h * 128 + f]      = f2bf((e0[i] * cs - e1[i] * sn) * scale);
    base[h * 128 + 64 + f] = f2bf((e0[i] * sn + e1[i] * cs) * scale);
  }
}

// ---------------- MFMA flash attention, causal GQA ------------------------
// Block = 256 thr = 4 waves; 64 q-rows/block (16/wave); KV-tile 64.
// Q frags in regs; K in LDS natural [kv][128+8]; V in LDS transposed
// [d][64+8] with kv-XOR swizzle; P via per-wave LDS round-trip.
__global__ __launch_bounds__(256) void attn_mfma(const u16* __restrict__ Qb,
                                                 const u16* __restrict__ KVb,
                                                 u16* __restrict__ Ob) {
  __shared__ u16 Ks[64 * 136];
  __shared__ u16 Vs[128 * 72];
  __shared__ u16 Ps[4 * 16 * 72];
  const int t = threadIdx.x;
  const int l = t & 63, w = t >> 6;
  const int lm = l & 15, quad = l >> 4;
  const int qt = (int)gridDim.x - 1 - (int)blockIdx.x;   // heavy blocks first
  const int h = blockIdx.y, b = blockIdx.z;
  const int kvh = h >> 2;
  const int wbase = w * (16 * 72);

  // Q fragments (A-layout: m=lm, k=quad*8+j), 4 chunks of K=32
  bf16x8 qf[4];
  {
    size_t qbase = ((size_t)(b * TT + qt * 64 + w * 16 + lm)) * DD + h * HDIM;
    #pragma unroll
    for (int c = 0; c < 4; ++c)
      qf[c] = *(const bf16x8*)(Qb + qbase + c * 32 + quad * 8);
  }

  f32x4 o[8];
  #pragma unroll
  for (int i = 0; i < 8; ++i) o[i] = (f32x4){0.f, 0.f, 0.f, 0.f};
  float m_[4] = {-1e30f, -1e30f, -1e30f, -1e30f};
  float l_[4] = {0.f, 0.f, 0.f, 0.f};

  for (int kt = 0; kt <= qt; ++kt) {
    const int kv0 = kt * 64;
    __syncthreads();   // prior-iter frag reads done before restaging
    // stage K: 64 x 128, natural layout, stride 136
    #pragma unroll
    for (int i = 0; i < 4; ++i) {
      int c = t + i * 256;
      int kv = c >> 4, dch = c & 15;
      *(uint4*)&Ks[kv * 136 + dch * 8] =
          *(const uint4*)(KVb + ((size_t)(b * TT + kv0 + kv)) * 1024 + kvh * 128 + dch * 8);
    }
    // stage V transposed: Vs[d][kv'] , kv' = kv ^ (((d>>3)&7)*8), stride 72
    #pragma unroll
    for (int i = 0; i < 2; ++i) {
      int c = t + i * 256;
      int kvp = c >> 4, dch = c & 15;
      const u16* src = KVb + ((size_t)(b * TT + kv0 + kvp * 2)) * 1024 + 512 + kvh * 128 + dch * 8;
      uint4 g0 = *(const uint4*)src;
      uint4 g1 = *(const uint4*)(src + 1024);
      const u16* p0 = (const u16*)&g0;
      const u16* p1 = (const u16*)&g1;
      #pragma unroll
      for (int jj = 0; jj < 8; ++jj) {
        int d = dch * 8 + jj;
        int kvs = (kvp * 2) ^ (((d >> 3) & 7) * 8);
        *(u32*)&Vs[d * 72 + kvs] = (u32)p0[jj] | ((u32)p1[jj] << 16);
      }
    }
    __syncthreads();

    // S = Q K^T : 4 n-tiles x 4 k-steps
    f32x4 s[4];
    #pragma unroll
    for (int nt = 0; nt < 4; ++nt) s[nt] = (f32x4){0.f, 0.f, 0.f, 0.f};
    #pragma unroll
    for (int ks = 0; ks < 4; ++ks) {
      #pragma unroll
      for (int nt = 0; nt < 4; ++nt) {
        bf16x8 kb = *(const bf16x8*)&Ks[(nt * 16 + lm) * 136 + ks * 32 + quad * 8];
        s[nt] = __builtin_amdgcn_mfma_f32_16x16x32_bf16(qf[ks], kb, s[nt], 0, 0, 0);
      }
    }

    // causal mask on diagonal tile
    if (kt == qt) {
      #pragma unroll
      for (int nt = 0; nt < 4; ++nt) {
        int col = nt * 16 + lm;
        #pragma unroll
        for (int r = 0; r < 4; ++r) {
          int row = w * 16 + quad * 4 + r;
          if (col > row) s[nt][r] = -1e30f;
        }
      }
    }

    // online softmax (rows quad*4+r; reduce over the 16 lanes of each quad)
    float alpha[4], p[4][4];
    #pragma unroll
    for (int r = 0; r < 4; ++r) {
      float mx = fmaxf(fmaxf(s[0][r], s[1][r]), fmaxf(s[2][r], s[3][r]));
      #pragma unroll
      for (int off = 1; off < 16; off <<= 1) mx = fmaxf(mx, __shfl_xor(mx, off));
      float mn = fmaxf(m_[r], mx);
      alpha[r] = exp2f((m_[r] - mn) * 1.4426950408889634f);
      m_[r] = mn;
      float sum = 0.f;
      #pragma unroll
      for (int nt = 0; nt < 4; ++nt) {
        float pv = exp2f((s[nt][r] - mn) * 1.4426950408889634f);
        p[nt][r] = pv;
        sum += pv;
      }
      #pragma unroll
      for (int off = 1; off < 16; off <<= 1) sum += __shfl_xor(sum, off);
      l_[r] = l_[r] * alpha[r] + sum;
    }

    // P -> LDS (C-layout positions), per-wave region (no barrier needed)
    #pragma unroll
    for (int nt = 0; nt < 4; ++nt)
      #pragma unroll
      for (int r = 0; r < 4; ++r)
        Ps[wbase + (quad * 4 + r) * 72 + nt * 16 + lm] = f2bf(p[nt][r]);

    // O *= alpha
    #pragma unroll
    for (int nt2 = 0; nt2 < 8; ++nt2)
      #pragma unroll
      for (int r = 0; r < 4; ++r) o[nt2][r] *= alpha[r];

    // O += P V : P back in A-layout, V from transposed-swizzled LDS
    #pragma unroll
    for (int ks2 = 0; ks2 < 2; ++ks2) {
      bf16x8 pa = *(const bf16x8*)&Ps[wbase + lm * 72 + ks2 * 32 + quad * 8];
      #pragma unroll
      for (int nt2 = 0; nt2 < 8; ++nt2) {
        int drow = nt2 * 16 + lm;
        int qbs = (ks2 * 4 + quad) ^ ((drow >> 3) & 7);
        bf16x8 vb = *(const bf16x8*)&Vs[drow * 72 + qbs * 8];
        o[nt2] = __builtin_amdgcn_mfma_f32_16x16x32_bf16(pa, vb, o[nt2], 0, 0, 0);
      }
    }
  }

  // epilogue: normalize and store bf16
  float invl[4];
  #pragma unroll
  for (int r = 0; r < 4; ++r) invl[r] = 1.f / l_[r];
  size_t obase = ((size_t)(b * TT + qt * 64 + w * 16)) * DD + h * HDIM;
  #pragma unroll
  for (int nt2 = 0; nt2 < 8; ++nt2)
    #pragma unroll
    for (int r = 0; r < 4; ++r)
      Ob[obase + (size_t)(quad * 4 + r) * DD + nt2 * 16 + lm] = f2bf(o[nt2][r] * invl[r]);
}

extern "C" void kernel_launch(void* const* d_in, const int* in_sizes, int n_in,
                              void* d_out, int out_size, void* d_ws, size_t ws_size,
                              hipStream_t stream) {
  const float* x  = (const float*)d_in[0];
  const float* Wq = (const float*)d_in[1];
  const float* Wk = (const float*)d_in[2];
  const float* Wv = (const float*)d_in[3];
  const float* Wo = (const float*)d_in[4];
  float* out = (float*)d_out;

  // ws layout (u16 elems), with aliased reuse:
  //   xb   @ 0        (8388608)   -> later Ob
  //   WqT  @ 8388608  (4194304)   -> later KVb (4096x1024)
  //   WkvT @ 12582912 (2097152)   [WkT rows 0..511 | WvT rows 512..1023]
  //   WoT  @ 14680064 (4194304)
  // Qb lives in d_out (bf16, 16MB of the 32MB fp32 out buffer).
  u16* xb   = (u16*)d_ws;
  u16* WqT  = xb + 8388608;
  u16* WkvT = xb + 12582912;
  u16* WoT  = xb + 14680064;
  u16* KVb  = WqT;                 // alias, live after gemm_q
  u16* Ob   = xb;                  // alias, live after all x-GEMMs
  u16* Qb   = (u16*)d_out;         // alias, dead before final GEMM writes

  const int M = BB * TT;           // 4096
  dim3 blk(256);

  // convert + transpose
  castf2b<<<8192, blk, 0, stream>>>(x, xb);
  tcast<<<dim3(64, 64), blk, 0, stream>>>(Wq, WqT, DD, DD);
  tcast<<<dim3(16, 64), blk, 0, stream>>>(Wk, WkvT, DD, 512);
  tcast<<<dim3(16, 64), blk, 0, stream>>>(Wv, WkvT + (size_t)512 * DD, DD, 512);
  tcast<<<dim3(64, 64), blk, 0, stream>>>(Wo, WoT, DD, DD);

  // projections (bf16 out)
  gemm_bf16<1><<<dim3(DD / 128, M / 128), blk, 0, stream>>>(xb, WqT, Qb, DD, DD);
  gemm_bf16<1><<<dim3(1024 / 128, M / 128), blk, 0, stream>>>(xb, WkvT, KVb, 1024, DD);

  // rope (softmax scale folded into Q)
  rope_bf16<<<M, blk, 0, stream>>>(Qb, DD, HH, 0.08838834764831845f);
  rope_bf16<<<M, blk, 0, stream>>>(KVb, 1024, KVHN, 1.0f);

  // attention
  attn_mfma<<<dim3(TT / 64, HH, BB), blk, 0, stream>>>(Qb, KVb, Ob);

  // output projection (fp32 out)
  gemm_bf16<0><<<dim3(DD / 128, M / 128), blk, 0, stream>>>(Ob, WoT, out, DD, DD);
}

// Round 4
// 341.454 us; speedup vs baseline: 8.7768x; 1.4557x over previous
//
#include <hip/hip_runtime.h>
#include <math.h>

#define BB 2
#define TT 2048
#define DD 2048
#define HH 16
#define KVHN 4
#define HDIM 128
#define NKV 3072   // packed q|k|v row width

typedef unsigned short u16;
typedef unsigned int u32;
typedef __bf16 bf16x8 __attribute__((ext_vector_type(8)));
typedef float  f32x4  __attribute__((ext_vector_type(4)));

#define AS1 __attribute__((address_space(1)))
#define AS3 __attribute__((address_space(3)))

__device__ __forceinline__ void dma16(const u16* g, u16* l) {
  __builtin_amdgcn_global_load_lds((const AS1 u32*)g, (AS3 u32*)l, 16, 0, 0);
}

__device__ __forceinline__ u16 f2bf(float f) {
  u32 u = __float_as_uint(f);
  u32 r = (u + 0x7FFFu + ((u >> 16) & 1u)) >> 16;
  return (u16)r;
}
__device__ __forceinline__ float bf2f(u32 h) { return __uint_as_float(h << 16); }

__device__ __forceinline__ u32 pack2(float a, float b) {
  union { __bf16 h[2]; u32 u; } cv;
  cv.h[0] = (__bf16)a; cv.h[1] = (__bf16)b;
  return cv.u;
}

// ---------------- cast fp32 -> bf16 ----------------------------------------
__global__ __launch_bounds__(256) void castf2b(const float* __restrict__ in,
                                               u16* __restrict__ out) {
  size_t i4 = (size_t)blockIdx.x * 256 + threadIdx.x;
  float4 v = *(const float4*)(in + i4 * 4);
  ushort4 o;
  o.x = f2bf(v.x); o.y = f2bf(v.y); o.z = f2bf(v.z); o.w = f2bf(v.w);
  *(ushort4*)(out + i4 * 4) = o;
}

// ---------------- transpose + cast: W[K][N] fp32 -> WT[N][K] bf16 ----------
__global__ __launch_bounds__(256) void tcast(const float* __restrict__ W,
                                             u16* __restrict__ WT,
                                             int K, int N) {
  __shared__ float tile[32][33];
  const int n0 = blockIdx.x * 32, k0 = blockIdx.y * 32;
  const int r = threadIdx.x >> 3;
  const int c4 = (threadIdx.x & 7) * 4;
  float4 v = *(const float4*)(W + (size_t)(k0 + r) * N + n0 + c4);
  tile[r][c4 + 0] = v.x; tile[r][c4 + 1] = v.y;
  tile[r][c4 + 2] = v.z; tile[r][c4 + 3] = v.w;
  __syncthreads();
  ushort4 o;
  o.x = f2bf(tile[c4 + 0][r]); o.y = f2bf(tile[c4 + 1][r]);
  o.z = f2bf(tile[c4 + 2][r]); o.w = f2bf(tile[c4 + 3][r]);
  *(ushort4*)(WT + (size_t)(n0 + r) * K + k0 + c4) = o;
}

// ---------------- m97-style MFMA GEMM: C = A @ BT^T ------------------------
// 128x128 tile, BK=32, global_load_lds width-16 staging, no-pad LDS.
template <int OUT_BF16>
__global__ __launch_bounds__(256) void gemm2(const u16* __restrict__ A,
                                             const u16* __restrict__ BT,
                                             void* __restrict__ Cv,
                                             int N, int K) {
  __shared__ u16 As[128 * 32];
  __shared__ u16 Bs[128 * 32];
  const int t = threadIdx.x;
  const int l = t & 63, w = t >> 6;
  const int lm = l & 15, quad = l >> 4;
  const int wm = w & 1, wn = w >> 1;
  const int m0 = blockIdx.y * 128, n0 = blockIdx.x * 128;
  const int wu = __builtin_amdgcn_readfirstlane(w);

  f32x4 acc[4][4];
  #pragma unroll
  for (int i = 0; i < 4; ++i)
    #pragma unroll
    for (int j = 0; j < 4; ++j) acc[i][j] = (f32x4){0.f, 0.f, 0.f, 0.f};

  for (int k0 = 0; k0 < K; k0 += 32) {
    __syncthreads();
    #pragma unroll
    for (int i = 0; i < 2; ++i) {
      int p0 = (wu * 2 + i) * 64;
      int p = p0 + l;
      int row = p >> 2, c = p & 3;
      dma16(A  + (size_t)(m0 + row) * K + k0 + c * 8, &As[p0 * 8]);
      dma16(BT + (size_t)(n0 + row) * K + k0 + c * 8, &Bs[p0 * 8]);
    }
    __syncthreads();
    bf16x8 a[4], bq[4];
    #pragma unroll
    for (int i = 0; i < 4; ++i)
      a[i] = *(const bf16x8*)&As[(wm * 64 + i * 16 + lm) * 32 + quad * 8];
    #pragma unroll
    for (int j = 0; j < 4; ++j)
      bq[j] = *(const bf16x8*)&Bs[(wn * 64 + j * 16 + lm) * 32 + quad * 8];
    #pragma unroll
    for (int i = 0; i < 4; ++i)
      #pragma unroll
      for (int j = 0; j < 4; ++j)
        acc[i][j] = __builtin_amdgcn_mfma_f32_16x16x32_bf16(a[i], bq[j], acc[i][j], 0, 0, 0);
  }

  #pragma unroll
  for (int i = 0; i < 4; ++i) {
    #pragma unroll
    for (int r = 0; r < 4; ++r) {
      size_t gr = (size_t)(m0 + wm * 64 + i * 16 + quad * 4 + r);
      #pragma unroll
      for (int j = 0; j < 4; ++j) {
        int gc = n0 + wn * 64 + j * 16 + lm;
        if (OUT_BF16) ((u16*)Cv)[gr * N + gc] = f2bf(acc[i][j][r]);
        else          ((float*)Cv)[gr * N + gc] = acc[i][j][r];
      }
    }
  }
}

// ---------------- RoPE in-place on packed QKV rows (q scaled) --------------
__global__ __launch_bounds__(256) void rope2(u16* p) {
  const int row = blockIdx.x;
  const int pos = row & (TT - 1);
  u16* base = p + (size_t)row * NKV;
  float e0[5], e1[5];
  #pragma unroll
  for (int i = 0; i < 5; ++i) {
    int item = threadIdx.x + i * 256;
    int h20 = item >> 6, f = item & 63;
    int col = (h20 < 16) ? h20 * 128 : 2048 + (h20 - 16) * 128;
    u32 u = *(const u32*)(base + col + 2 * f);
    e0[i] = bf2f(u & 0xffffu);
    e1[i] = bf2f(u >> 16);
  }
  __syncthreads();
  #pragma unroll
  for (int i = 0; i < 5; ++i) {
    int item = threadIdx.x + i * 256;
    int h20 = item >> 6, f = item & 63;
    int col = (h20 < 16) ? h20 * 128 : 2048 + (h20 - 16) * 128;
    float sc = (h20 < 16) ? 0.08838834764831845f : 1.0f;
    float inv = exp2f((float)f * -0.20762050593046898f);  // 10000^(-f/64)
    float ang = (float)pos * inv;
    float sn = sinf(ang), cs = cosf(ang);
    base[col + f]      = f2bf((e0[i] * cs - e1[i] * sn) * sc);
    base[col + 64 + f] = f2bf((e0[i] * sn + e1[i] * cs) * sc);
  }
}

// ---------------- V transpose: QKV v-part -> Vt[(b*4+vh)*128+d][T] ---------
__global__ __launch_bounds__(256) void vtrans(const u16* __restrict__ QKV,
                                              u16* __restrict__ Vt) {
  __shared__ u16 tl[64][72];
  const int t0 = blockIdx.x * 64;
  const int y  = blockIdx.y;        // 0..7
  const int b  = blockIdx.z;
  #pragma unroll
  for (int i = 0; i < 2; ++i) {
    int idx = threadIdx.x + i * 256;
    int r = idx >> 3, c = (idx & 7) * 8;
    *(uint4*)&tl[r][c] =
        *(const uint4*)(QKV + (size_t)(b * TT + t0 + r) * NKV + 2560 + y * 64 + c);
  }
  __syncthreads();
  const int vh = y >> 1;
  #pragma unroll
  for (int i = 0; i < 2; ++i) {
    int idx = threadIdx.x + i * 256;
    int dr = idx >> 3, tc = (idx & 7) * 8;
    u16 tmp[8];
    #pragma unroll
    for (int j = 0; j < 8; ++j) tmp[j] = tl[tc + j][dr];
    int dloc = (y & 1) * 64 + dr;
    *(uint4*)(Vt + (size_t)((b * KVHN + vh) * HDIM + dloc) * TT + t0 + tc) =
        *(const uint4*)tmp;
  }
}

// ---------------- MFMA flash attention v2 (S^T form, DMA dbuf) -------------
// Block: 256 thr = 4 waves; q-tile pair {px, 31-px} (2x64 rows); KV-tile 64.
__global__ __launch_bounds__(256, 2) void attn2(const u16* __restrict__ QKV,
                                                const u16* __restrict__ Vt,
                                                u16* __restrict__ Ob) {
  __shared__ u16 KsA[64 * 128], KsB[64 * 128];
  __shared__ u16 VsA[128 * 64], VsB[128 * 64];
  __shared__ u16 Pw[4 * 2048];
  const int t = threadIdx.x;
  const int l = t & 63, w = t >> 6;
  const int lm = l & 15, quad = l >> 4;
  const int px = blockIdx.x, h = blockIdx.y, b = blockIdx.z;
  const int kvh = h >> 2;
  const int qlo = px * 64, qhi = (31 - px) * 64;
  const int last = 31 - px;
  const int wu = __builtin_amdgcn_readfirstlane(w);
  u16* pwv = &Pw[w * 2048];
  constexpr float L2E = 1.4426950408889634f;

  // Q fragments (B-operand: rows q=lm, contiguous k)
  bf16x8 qf[2][4];
  {
    size_t r0 = (size_t)(b * TT + qlo + w * 16 + lm) * NKV + h * HDIM;
    size_t r1 = (size_t)(b * TT + qhi + w * 16 + lm) * NKV + h * HDIM;
    #pragma unroll
    for (int ks = 0; ks < 4; ++ks) {
      qf[0][ks] = *(const bf16x8*)(QKV + r0 + ks * 32 + quad * 8);
      qf[1][ks] = *(const bf16x8*)(QKV + r1 + ks * 32 + quad * 8);
    }
  }

  f32x4 o[8][2];
  #pragma unroll
  for (int i = 0; i < 8; ++i)
    #pragma unroll
    for (int n = 0; n < 2; ++n) o[i][n] = (f32x4){0.f, 0.f, 0.f, 0.f};
  float m_[2] = {-1e30f, -1e30f}, l_[2] = {0.f, 0.f};

  auto stageK = [&](int kt, u16* dst) {
    #pragma unroll
    for (int i = 0; i < 4; ++i) {
      int p0 = (wu * 4 + i) * 64;
      int p = p0 + l;
      int row = p >> 4, cp = p & 15, cl = cp ^ (row & 15);
      dma16(QKV + (size_t)(b * TT + kt * 64 + row) * NKV + 2048 + kvh * HDIM + cl * 8,
            dst + p0 * 8);
    }
  };
  auto stageV = [&](int kt, u16* dst) {
    #pragma unroll
    for (int i = 0; i < 4; ++i) {
      int p0 = (wu * 4 + i) * 64;
      int p = p0 + l;
      int d = p >> 3, cp = p & 7, cl = cp ^ (d & 7);
      dma16(Vt + (size_t)((b * KVHN + kvh) * HDIM + d) * TT + kt * 64 + cl * 8,
            dst + p0 * 8);
    }
  };

  auto body = [&](int kt, u16* kcur, u16* vcur, u16* knext, u16* vnext) {
    __syncthreads();                       // cur buffers landed; prev reads done
    const bool pf = kt < last;
    if (pf) stageV(kt + 1, vnext);
    const bool lo = (kt <= px);

    // S^T = K . Q^T
    f32x4 s[4][2];
    #pragma unroll
    for (int mt = 0; mt < 4; ++mt) {
      s[mt][0] = (f32x4){0.f, 0.f, 0.f, 0.f};
      s[mt][1] = (f32x4){0.f, 0.f, 0.f, 0.f};
    }
    #pragma unroll
    for (int ks = 0; ks < 4; ++ks) {
      #pragma unroll
      for (int mt = 0; mt < 4; ++mt) {
        bf16x8 kb = *(const bf16x8*)&kcur[(mt * 16 + lm) * 128 + (((ks * 4 + quad) ^ lm) * 8)];
        if (lo) s[mt][0] = __builtin_amdgcn_mfma_f32_16x16x32_bf16(kb, qf[0][ks], s[mt][0], 0, 0, 0);
        s[mt][1] = __builtin_amdgcn_mfma_f32_16x16x32_bf16(kb, qf[1][ks], s[mt][1], 0, 0, 0);
      }
    }
    if (pf) stageK(kt + 1, knext);

    // causal mask on diagonal tiles
    if (kt == px) {
      #pragma unroll
      for (int mt = 0; mt < 4; ++mt)
        #pragma unroll
        for (int r = 0; r < 4; ++r) {
          int kv = kt * 64 + mt * 16 + quad * 4 + r;
          if (kv > qlo + w * 16 + lm) s[mt][0][r] = -1e30f;
        }
    }
    if (kt == last) {
      #pragma unroll
      for (int mt = 0; mt < 4; ++mt)
        #pragma unroll
        for (int r = 0; r < 4; ++r) {
          int kv = kt * 64 + mt * 16 + quad * 4 + r;
          if (kv > qhi + w * 16 + lm) s[mt][1][r] = -1e30f;
        }
    }

    // online softmax per q-tile (reduce: in-lane 16 + cross-quad shfl x2)
    float al[2] = {1.f, 1.f};
    #pragma unroll
    for (int nt = 0; nt < 2; ++nt) {
      if (nt == 0 && !lo) continue;
      float mx = -1e30f;
      #pragma unroll
      for (int mt = 0; mt < 4; ++mt)
        #pragma unroll
        for (int r = 0; r < 4; ++r) mx = fmaxf(mx, s[mt][nt][r]);
      mx = fmaxf(mx, __shfl_xor(mx, 16));
      mx = fmaxf(mx, __shfl_xor(mx, 32));
      float mn = fmaxf(m_[nt], mx);
      al[nt] = exp2f((m_[nt] - mn) * L2E);
      m_[nt] = mn;
      float sum = 0.f;
      #pragma unroll
      for (int mt = 0; mt < 4; ++mt)
        #pragma unroll
        for (int r = 0; r < 4; ++r) {
          float pv = exp2f((s[mt][nt][r] - mn) * L2E);
          s[mt][nt][r] = pv;
          sum += pv;
        }
      sum += __shfl_xor(sum, 16);
      sum += __shfl_xor(sum, 32);
      l_[nt] = l_[nt] * al[nt] + sum;

      // P -> LDS (b64 swizzled), per-wave region
      #pragma unroll
      for (int mt = 0; mt < 4; ++mt) {
        u32 p01 = pack2(s[mt][nt][0], s[mt][nt][1]);
        u32 p23 = pack2(s[mt][nt][2], s[mt][nt][3]);
        int phys = (mt * 2 + (quad >> 1)) ^ (lm & 7);
        int addr = (nt * 16 + lm) * 64 + phys * 8 + (quad & 1) * 4;
        uint2 uv; uv.x = p01; uv.y = p23;
        *(uint2*)&pwv[addr] = uv;
      }
      // O^T rescale
      if (__any(al[nt] < 1.0f)) {
        #pragma unroll
        for (int mt2 = 0; mt2 < 8; ++mt2)
          #pragma unroll
          for (int r = 0; r < 4; ++r) o[mt2][nt][r] *= al[nt];
      }
    }

    // O^T += V^T . P^T
    #pragma unroll
    for (int ks2 = 0; ks2 < 2; ++ks2) {
      int coff = ((ks2 * 4 + quad) ^ (lm & 7)) * 8;
      bf16x8 pb0, pb1;
      if (lo) pb0 = *(const bf16x8*)&pwv[lm * 64 + coff];
      pb1 = *(const bf16x8*)&pwv[(16 + lm) * 64 + coff];
      #pragma unroll
      for (int mt2 = 0; mt2 < 8; ++mt2) {
        bf16x8 vb = *(const bf16x8*)&vcur[(mt2 * 16 + lm) * 64 + coff];
        if (lo) o[mt2][0] = __builtin_amdgcn_mfma_f32_16x16x32_bf16(vb, pb0, o[mt2][0], 0, 0, 0);
        o[mt2][1] = __builtin_amdgcn_mfma_f32_16x16x32_bf16(vb, pb1, o[mt2][1], 0, 0, 0);
      }
    }
  };

  stageK(0, KsA); stageV(0, VsA);
  for (int kt = 0; kt <= last; ++kt) {
    if ((kt & 1) == 0) body(kt, KsA, VsA, KsB, VsB);
    else               body(kt, KsB, VsB, KsA, VsA);
  }

  // epilogue: O^T -> LDS (transpose) -> coalesced bf16 stores
  #pragma unroll
  for (int nt = 0; nt < 2; ++nt) {
    float inv = 1.f / l_[nt];
    #pragma unroll
    for (int mt2 = 0; mt2 < 8; ++mt2) {
      u32 a0 = pack2(o[mt2][nt][0] * inv, o[mt2][nt][1] * inv);
      u32 a1 = pack2(o[mt2][nt][2] * inv, o[mt2][nt][3] * inv);
      int phys = (mt2 * 2 + (quad >> 1)) ^ (lm & 7);
      int addr = lm * 128 + phys * 8 + (quad & 1) * 4;
      uint2 uv; uv.x = a0; uv.y = a1;
      *(uint2*)&pwv[addr] = uv;
    }
    int qt0 = nt ? qhi : qlo;
    // FIX (R3 bug): tile is 16 rows x 16 chunks = 256 chunks; was i<2 with
    // row=p>>3, cl=p&7 -> only d<64 stored. Now 4 iters, full 128 dims.
    #pragma unroll
    for (int i = 0; i < 4; ++i) {
      int p = i * 64 + l;
      int row = p >> 4, cl = p & 15;
      int cph = cl ^ (row & 7);
      uint4 val = *(const uint4*)&pwv[row * 128 + cph * 8];
      *(uint4*)(Ob + (size_t)(b * TT + qt0 + w * 16 + row) * DD + h * HDIM + cl * 8) = val;
    }
  }
}

extern "C" void kernel_launch(void* const* d_in, const int* in_sizes, int n_in,
                              void* d_out, int out_size, void* d_ws, size_t ws_size,
                              hipStream_t stream) {
  const float* x  = (const float*)d_in[0];
  const float* Wq = (const float*)d_in[1];
  const float* Wk = (const float*)d_in[2];
  const float* Wv = (const float*)d_in[3];
  const float* Wo = (const float*)d_in[4];
  float* out = (float*)d_out;

  // ws (u16 elems): xb @0 (8M, -> Ob) | WqkvT @8M (6M, -> Vt) | WoT @14.68M (4M)
  u16* xb    = (u16*)d_ws;
  u16* WqkvT = xb + 8388608;
  u16* WoT   = xb + 14680064;
  u16* Vt    = WqkvT;               // alias, live after QKV GEMM
  u16* Ob    = xb;                  // alias, live after QKV GEMM
  u16* QKVb  = (u16*)d_out;         // bf16 [4096][3072] in the 32MB out buffer

  dim3 blk(256);
  castf2b<<<8192, blk, 0, stream>>>(x, xb);
  tcast<<<dim3(64, 64), blk, 0, stream>>>(Wq, WqkvT, DD, DD);
  tcast<<<dim3(16, 64), blk, 0, stream>>>(Wk, WqkvT + (size_t)2048 * DD, DD, 512);
  tcast<<<dim3(16, 64), blk, 0, stream>>>(Wv, WqkvT + (size_t)2560 * DD, DD, 512);
  tcast<<<dim3(64, 64), blk, 0, stream>>>(Wo, WoT, DD, DD);

  gemm2<1><<<dim3(NKV / 128, 32), blk, 0, stream>>>(xb, WqkvT, QKVb, NKV, DD);
  rope2<<<BB * TT, blk, 0, stream>>>(QKVb);
  vtrans<<<dim3(32, 8, BB), blk, 0, stream>>>(QKVb, Vt);
  attn2<<<dim3(16, HH, BB), blk, 0, stream>>>(QKVb, Vt, Ob);
  gemm2<0><<<dim3(DD / 128, 32), blk, 0, stream>>>(Ob, WoT, out, DD, DD);
}